// Round 13
// baseline (663.052 us; speedup 1.0000x reference)
//
#include <hip/hip_runtime.h>
#include <math.h>

#define HH 512
#define WW 512
#define NB 64
#define CH_STRIDE (HH*WW)
#define IMG_STRIDE (3*CH_STRIDE)

// 5-tap Gaussian, sigma=1.0 (matches cv2.getGaussianKernel(5,1.0) in f32)
#define GK0 0.0544886846f
#define GK1 0.2442013419f
#define GK2 0.4026199468f

__device__ __forceinline__ float quant255(float v) {
    // floor(clip(v*255, 0, 255)); _rn ops to avoid FMA contraction changing boundaries
    return floorf(fminf(fmaxf(__fmul_rn(v, 255.0f), 0.0f), 255.0f));
}
__device__ __forceinline__ float gray255(float qa, float qb, float qc) {
    // rint = round-half-even, matches jnp.round; stays in x255 domain (no /255)
    return rintf(__fadd_rn(__fadd_rn(__fmul_rn(0.299f, qa), __fmul_rn(0.587f, qb)),
                           __fmul_rn(0.114f, qc)));
}

// v9: 3 waves/SIMD occupancy push. v8 showed hist/L1/prefetch-depth are not
// the stall; occupancy has been grid+register pinned at 2/SIMD. The v8 body's
// live state ~165 VGPR fits the 170 cap of __launch_bounds__(256,3), and
// 16-row chunks give 4096 waves (1024 blocks) so 3/SIMD is actually usable.
// This is v4's geometry with cap 170 (not 128) and the shuffle-free float2-halo
// body (~35 fewer regs) — the two fixes for v4's spill. 1-deep prefetch
// (2-deep measured neutral in v8). WRITE_SIZE is the spill sentinel.
__global__ __launch_bounds__(256, 3)
void noise_main(const float* __restrict__ x, float* __restrict__ gsums,
                unsigned int* __restrict__ ghist)
{
    __shared__ unsigned int lhist[4][4][50];
    const int tid  = threadIdx.x;
    const int lane = tid & 63;
    const int wid  = tid >> 6;
    for (int i = tid; i < 800; i += 256) ((unsigned int*)lhist)[i] = 0u;
    __syncthreads();

    // XCD-aware bijective swizzle: 1024 blocks, 8 XCDs -> XCD k gets images 8k..8k+7
    const int rawblk = blockIdx.x;
    const int blk = (rawblk & 7) * 128 + (rawblk >> 3);

    const int b     = blk >> 4;        // image 0..63 (16 blocks per image)
    const int strip = (blk >> 3) & 1;  // 0..1 (cols 0..255 / 256..511)
    const int cg    = blk & 7;         // chunk group 0..7
    const int chunk = cg * 4 + wid;    // 0..31
    const int R0    = chunk * 16;      // first output row (16 rows per wave)
    const int X0    = strip * 256;     // first col of strip
    const int gcol  = X0 + lane * 4;

    // aligned halo float2 source cols; clamped in-bounds at true image edges
    // (edge lanes' values are replaced by reflect fixup, so target is arbitrary)
    const int cLo = (gcol == 0)   ? 0   : gcol - 2;   // cols gcol-2, gcol-1
    const int cHi = (gcol == 508) ? 504 : gcol + 4;   // cols gcol+4, gcol+5

    const float* pa = x + (size_t)b * IMG_STRIDE;
    const float* pb = pa + CH_STRIDE;
    const float* pc = pb + CH_STRIDE;

    // horizontal-blur rings [slot][col], slot = t % 5 (static via unroll 5)
    float hrA[5][4], hrB[5][4], hrC[5][4], hrG[5][4];
    // raw-center delays (row t-1, t-2)
    float d1A[4]={0,0,0,0}, d1B[4]={0,0,0,0}, d1C[4]={0,0,0,0}, d1G[4]={0,0,0,0};
    float d2A[4]={0,0,0,0}, d2B[4]={0,0,0,0}, d2C[4]={0,0,0,0}, d2G[4]={0,0,0,0};
    float sA=0.f,qA=0.f,sB=0.f,qB=0.f,sC=0.f,qC=0.f,sG=0.f,qG=0.f;

    // current row + prefetched next row (1-deep)
    float4 va, vb, vc;       float2 La, Lb, Lc, Ra, Rb, Rc;
    float4 nva, nvb, nvc;    float2 nLa, nLb, nLc, nRa, nRb, nRc;

#define LOADROW(T, VA_,VB_,VC_, LA_,LB_,LC_, RA_,RB_,RC_) do {                  \
        int r_ = R0 - 2 + (T);                                                  \
        r_ = (r_ < 0) ? -r_ : ((r_ >= HH) ? (2*(HH-1) - r_) : r_);              \
        const int ro_ = r_ * WW;                                                \
        VA_ = *(const float4*)(pa + ro_ + gcol);                                \
        VB_ = *(const float4*)(pb + ro_ + gcol);                                \
        VC_ = *(const float4*)(pc + ro_ + gcol);                                \
        LA_ = *(const float2*)(pa + ro_ + cLo);                                 \
        LB_ = *(const float2*)(pb + ro_ + cLo);                                 \
        LC_ = *(const float2*)(pc + ro_ + cLo);                                 \
        RA_ = *(const float2*)(pa + ro_ + cHi);                                 \
        RB_ = *(const float2*)(pb + ro_ + cHi);                                 \
        RC_ = *(const float2*)(pc + ro_ + cHi);                                 \
    } while (0)

    // preload row-step 0
    LOADROW(0, va,vb,vc, La,Lb,Lc, Ra,Rb,Rc);

    #pragma unroll 1
    for (int tb = 0; tb < 4; ++tb) {
        #pragma unroll
        for (int u = 0; u < 5; ++u) {
            const int t = tb * 5 + u;          // row step 0..19; slot = u
            // ---- prefetch next row: whole body below is its cover ----
            if (t + 1 < 20)
                LOADROW(t + 1, nva,nvb,nvc, nLa,nLb,nLc, nRa,nRb,nRc);

            // quantized gray (x255 domain), own 4 cols
            float g0 = gray255(quant255(va.x), quant255(vb.x), quant255(vc.x));
            float g1 = gray255(quant255(va.y), quant255(vb.y), quant255(vc.y));
            float g2 = gray255(quant255(va.z), quant255(vb.z), quant255(vc.z));
            float g3 = gray255(quant255(va.w), quant255(vb.w), quant255(vc.w));

            // raw halo from the aligned float2 neighbor reads (no shuffles)
            float l2a = La.x, l1a = La.y, r0a = Ra.x, r1a = Ra.y;
            float l2b = Lb.x, l1b = Lb.y, r0b = Rb.x, r1b = Rb.y;
            float l2c = Lc.x, l1c = Lc.y, r0c = Rc.x, r1c = Rc.y;
            // gray halo via shuffle of computed gray (4 shuffles only)
            float gl2 = __shfl_up(g2, 1),   gl1 = __shfl_up(g3, 1);
            float gr0 = __shfl_down(g0, 1), gr1 = __shfl_down(g1, 1);

            if (lane == 0) {
                if (X0 == 0) { // reflect-101: col -2 -> col 2 (.z), col -1 -> col 1 (.y)
                    l2a = va.z; l1a = va.y; l2b = vb.z; l1b = vb.y; l2c = vc.z; l1c = vc.y;
                    gl2 = g2;   gl1 = g1;
                } else {       // raw halo valid (cols 254,255); recompute gray halo
                    gl2 = gray255(quant255(La.x), quant255(Lb.x), quant255(Lc.x));
                    gl1 = gray255(quant255(La.y), quant255(Lb.y), quant255(Lc.y));
                }
            }
            if (lane == 63) {
                if (X0 == 0) { // raw halo valid (cols 256,257); recompute gray halo
                    gr0 = gray255(quant255(Ra.x), quant255(Rb.x), quant255(Rc.x));
                    gr1 = gray255(quant255(Ra.y), quant255(Rb.y), quant255(Rc.y));
                } else {       // reflect-101: col 512 -> 510 (.z), col 513 -> 509 (.y)
                    r0a = va.z; r1a = va.y; r0b = vb.z; r1b = vb.y; r0c = vc.z; r1c = vc.y;
                    gr0 = g2;   gr1 = g1;
                }
            }

            // horizontal blur of row t -> ring slot u
            hrA[u][0] = GK0*(l2a+va.z) + GK1*(l1a+va.y) + GK2*va.x;
            hrA[u][1] = GK0*(l1a+va.w) + GK1*(va.x+va.z) + GK2*va.y;
            hrA[u][2] = GK0*(va.x+r0a) + GK1*(va.y+va.w) + GK2*va.z;
            hrA[u][3] = GK0*(va.y+r1a) + GK1*(va.z+r0a) + GK2*va.w;
            hrB[u][0] = GK0*(l2b+vb.z) + GK1*(l1b+vb.y) + GK2*vb.x;
            hrB[u][1] = GK0*(l1b+vb.w) + GK1*(vb.x+vb.z) + GK2*vb.y;
            hrB[u][2] = GK0*(vb.x+r0b) + GK1*(vb.y+vb.w) + GK2*vb.z;
            hrB[u][3] = GK0*(vb.y+r1b) + GK1*(vb.z+r0b) + GK2*vb.w;
            hrC[u][0] = GK0*(l2c+vc.z) + GK1*(l1c+vc.y) + GK2*vc.x;
            hrC[u][1] = GK0*(l1c+vc.w) + GK1*(vc.x+vc.z) + GK2*vc.y;
            hrC[u][2] = GK0*(vc.x+r0c) + GK1*(vc.y+vc.w) + GK2*vc.z;
            hrC[u][3] = GK0*(vc.y+r1c) + GK1*(vc.z+r0c) + GK2*vc.w;
            hrG[u][0] = GK0*(gl2+g2) + GK1*(gl1+g1) + GK2*g0;
            hrG[u][1] = GK0*(gl1+g3) + GK1*(g0+g2)  + GK2*g1;
            hrG[u][2] = GK0*(g0+gr0) + GK1*(g1+g3)  + GK2*g2;
            hrG[u][3] = GK0*(g1+gr1) + GK1*(g2+gr0) + GK2*g3;

            // output: center row t-2 (valid for t in [4,19])
            if (t >= 4) {
                const int s0=(u+1)%5, s1=(u+2)%5, s2=(u+3)%5, s3=(u+4)%5, s4=u;
                #pragma unroll
                for (int j = 0; j < 4; ++j) {
                    float bl, v;
                    bl = GK0*(hrA[s0][j]+hrA[s4][j]) + GK1*(hrA[s1][j]+hrA[s3][j]) + GK2*hrA[s2][j];
                    v  = d2A[j] - bl;  sA += v;  qA = fmaf(v, v, qA);
                    bl = GK0*(hrB[s0][j]+hrB[s4][j]) + GK1*(hrB[s1][j]+hrB[s3][j]) + GK2*hrB[s2][j];
                    v  = d2B[j] - bl;  sB += v;  qB = fmaf(v, v, qB);
                    bl = GK0*(hrC[s0][j]+hrC[s4][j]) + GK1*(hrC[s1][j]+hrC[s3][j]) + GK2*hrC[s2][j];
                    v  = d2C[j] - bl;  sC += v;  qC = fmaf(v, v, qC);
                    bl = GK0*(hrG[s0][j]+hrG[s4][j]) + GK1*(hrG[s1][j]+hrG[s3][j]) + GK2*hrG[s2][j];
                    v  = d2G[j] - bl;  sG += v;  qG = fmaf(v, v, qG);
                    // histogram: x255 domain, bins over (-0.5,0.5)*255, right edge inclusive
                    if (v >= -127.5f && v <= 127.5f) {
                        int idx = (int)((v + 127.5f) * 0.19607843137254902f); // 50/255
                        idx = idx > 49 ? 49 : idx;
                        atomicAdd(&lhist[wid][lane & 3][idx], 1u);
                    }
                }
            }

            // shift raw-center delays
            #pragma unroll
            for (int j = 0; j < 4; ++j) { d2A[j]=d1A[j]; d2B[j]=d1B[j]; d2C[j]=d1C[j]; d2G[j]=d1G[j]; }
            d1A[0]=va.x; d1A[1]=va.y; d1A[2]=va.z; d1A[3]=va.w;
            d1B[0]=vb.x; d1B[1]=vb.y; d1B[2]=vb.z; d1B[3]=vb.w;
            d1C[0]=vc.x; d1C[1]=vc.y; d1C[2]=vc.z; d1C[3]=vc.w;
            d1G[0]=g0;   d1G[1]=g1;   d1G[2]=g2;   d1G[3]=g3;

            // rotate prefetched row into current (renamed away inside the unroll)
            va = nva;  vb = nvb;  vc = nvc;
            La = nLa;  Lb = nLb;  Lc = nLc;  Ra = nRa;  Rb = nRb;  Rc = nRc;
        }
    }
#undef LOADROW

    // wave-reduce 8 accumulators -> one global atomic each
    float acc[8] = {sA, qA, sB, qB, sC, qC, sG, qG};
    #pragma unroll
    for (int f = 0; f < 8; ++f) {
        float v = acc[f];
        #pragma unroll
        for (int o = 32; o > 0; o >>= 1) v += __shfl_down(v, o);
        if (lane == 0) atomicAdd(&gsums[b*8 + f], v);
    }
    __syncthreads();
    if (tid < 50) {
        unsigned int h = 0;
        #pragma unroll
        for (int w = 0; w < 4; ++w)
            #pragma unroll
            for (int p = 0; p < 4; ++p) h += lhist[w][p][tid];
        atomicAdd(&ghist[b*50 + tid], h);
    }
}

// One lane per image: stats -> feats[6] -> 6->32->64 ReLU MLP
__global__ __launch_bounds__(64)
void noise_final(const float* __restrict__ gsums, const unsigned int* __restrict__ ghist,
                 const float* __restrict__ W1, const float* __restrict__ b1,
                 const float* __restrict__ W2, const float* __restrict__ b2,
                 float* __restrict__ out)
{
    const int b = threadIdx.x;
    if (b >= NB) return;
    const float invN = 1.0f / (float)(HH*WW);
    float feats[6];
    {   // gray variance/std (undo x255 scaling)
        float s = gsums[b*8 + 6], q = gsums[b*8 + 7];
        float m = s * invN;
        float var255 = q * invN - m*m;
        var255 = var255 < 0.f ? 0.f : var255;
        float var = var255 * (1.0f/65025.0f);
        feats[0] = var; feats[1] = sqrtf(var);
    }
    {   // histogram entropy
        float tot = 0.f;
        for (int i = 0; i < 50; ++i) tot += (float)ghist[b*50 + i];
        float inv = 1.0f / (tot + 1e-10f);
        float e = 0.f;
        for (int i = 0; i < 50; ++i) {
            float p = (float)ghist[b*50 + i] * inv;
            e -= p * log2f(p + 1e-10f);
        }
        feats[2] = e;
    }
    for (int c = 0; c < 3; ++c) {
        float s = gsums[b*8 + 2*c], q = gsums[b*8 + 2*c + 1];
        float m = s * invN;
        float v = q * invN - m*m;
        feats[3+c] = sqrtf(v < 0.f ? 0.f : v);
    }
    float h[32];
    #pragma unroll
    for (int i = 0; i < 32; ++i) {
        float a = b1[i];
        #pragma unroll
        for (int j = 0; j < 6; ++j) a = fmaf(feats[j], W1[i*6 + j], a);
        h[i] = a > 0.f ? a : 0.f;
    }
    for (int k = 0; k < 64; ++k) {
        float a = b2[k];
        #pragma unroll
        for (int j = 0; j < 32; ++j) a = fmaf(h[j], W2[k*32 + j], a);
        out[b*64 + k] = a > 0.f ? a : 0.f;
    }
}

extern "C" void kernel_launch(void* const* d_in, const int* in_sizes, int n_in,
                              void* d_out, int out_size, void* d_ws, size_t ws_size,
                              hipStream_t stream) {
    (void)in_sizes; (void)n_in; (void)out_size; (void)ws_size;
    const float* x  = (const float*)d_in[0];
    const float* W1 = (const float*)d_in[1];
    const float* b1 = (const float*)d_in[2];
    const float* W2 = (const float*)d_in[3];
    const float* b2 = (const float*)d_in[4];
    float* out = (float*)d_out;

    float* gsums = (float*)d_ws;                                   // [64][8]
    unsigned int* ghist = (unsigned int*)((char*)d_ws + NB*8*4);   // [64][50]
    hipMemsetAsync(d_ws, 0, NB*8*4 + NB*50*4, stream);

    hipLaunchKernelGGL(noise_main, dim3(1024), dim3(256), 0, stream, x, gsums, ghist);
    hipLaunchKernelGGL(noise_final, dim3(1), dim3(64), 0, stream,
                       gsums, ghist, W1, b1, W2, b2, out);
}

// Round 14
// 323.191 us; speedup vs baseline: 2.0516x; 2.0516x over previous
//
#include <hip/hip_runtime.h>
#include <math.h>

#define HH 512
#define WW 512
#define NB 64
#define CH_STRIDE (HH*WW)
#define IMG_STRIDE (3*CH_STRIDE)

// 5-tap Gaussian, sigma=1.0 (matches cv2.getGaussianKernel(5,1.0) in f32)
#define GK0 0.0544886846f
#define GK1 0.2442013419f
#define GK2 0.4026199468f

__device__ __forceinline__ float quant255(float v) {
    // floor(clip(v*255, 0, 255)); _rn ops to avoid FMA contraction changing boundaries
    return floorf(fminf(fmaxf(__fmul_rn(v, 255.0f), 0.0f), 255.0f));
}
__device__ __forceinline__ float gray255(float qa, float qb, float qc) {
    // rint = round-half-even, matches jnp.round; stays in x255 domain (no /255)
    return rintf(__fadd_rn(__fadd_rn(__fmul_rn(0.299f, qa), __fmul_rn(0.587f, qb)),
                           __fmul_rn(0.114f, qc)));
}

// FINAL = v7 (measured best: 325.7us, absmax 0). Ledger:
//  - float4/lane, 256-col strips, 32-row chunks, 512 blocks, 2 waves/SIMD.
//  - Shuffle-free raw halo: each lane loads aligned neighbor float4s (vL/vR);
//    only 4 gray shuffles remain. (+5us vs v6)
//  - XCD-bijective swizzle; 1-deep row prefetch. (+5us vs R1)
//  - Occupancy pushes all measured REGRESSIONS: live state >170 VGPR, so
//    bounds(256,3)/(256,4) spill to scratch (v9: VGPR=84, WRITE 396MB, 430us;
//    v4: 440us); float2 small-chunk geometries inflate per-wave overhead
//    (v3: 119us, v5: 209us). 2 waves/SIMD is the register-feasible max.
//  - Prefetch 2-deep, 4-way hist split, float2 halos: all neutral (v8).
__global__ __launch_bounds__(256, 2)
void noise_main(const float* __restrict__ x, float* __restrict__ gsums,
                unsigned int* __restrict__ ghist)
{
    __shared__ unsigned int lhist[4][2][50];
    const int tid  = threadIdx.x;
    const int lane = tid & 63;
    const int wid  = tid >> 6;
    for (int i = tid; i < 400; i += 256) ((unsigned int*)lhist)[i] = 0u;
    __syncthreads();

    // XCD-aware bijective swizzle: 512 blocks, 8 XCDs -> XCD k gets logical
    // blocks 64k..64k+63 = images 8k..8k+7 (all halo/atomic traffic in-XCD).
    const int rawblk = blockIdx.x;
    const int blk = (rawblk & 7) * 64 + (rawblk >> 3);

    const int b     = blk >> 3;        // image 0..63
    const int strip = (blk >> 2) & 1;  // 0..1 (cols 0..255 / 256..511)
    const int cg    = blk & 3;         // chunk group
    const int chunk = cg * 4 + wid;    // 0..15
    const int R0    = chunk * 32;      // first output row
    const int X0    = strip * 256;     // first col of strip
    const int gcol  = X0 + lane * 4;

    // halo-source columns: clamped at true image edges (values replaced by
    // reflect fixup there, so clamp target is arbitrary but in-bounds)
    const int cLo = (gcol == 0)   ? 0   : gcol - 4;
    const int cHi = (gcol == 508) ? 504 : gcol + 4;

    const float* pa = x + (size_t)b * IMG_STRIDE;
    const float* pb = pa + CH_STRIDE;
    const float* pc = pb + CH_STRIDE;

    // horizontal-blur rings [slot][col], slot = t % 5 (static via unroll 5)
    float hrA[5][4], hrB[5][4], hrC[5][4], hrG[5][4];
    // raw-center delays (row t-1, t-2)
    float d1A[4]={0,0,0,0}, d1B[4]={0,0,0,0}, d1C[4]={0,0,0,0}, d1G[4]={0,0,0,0};
    float d2A[4]={0,0,0,0}, d2B[4]={0,0,0,0}, d2C[4]={0,0,0,0}, d2G[4]={0,0,0,0};
    float sA=0.f,qA=0.f,sB=0.f,qB=0.f,sC=0.f,qC=0.f,sG=0.f,qG=0.f;

    // current row (v=center, L/R = aligned halo lines) + prefetched next row
    float4 va, vb, vc, vLa, vLb, vLc, vRa, vRb, vRc;
    float4 nva, nvb, nvc, nvLa, nvLb, nvLc, nvRa, nvRb, nvRc;

#define LOADROW(T, VA_,VB_,VC_, LA_,LB_,LC_, RA_,RB_,RC_) do {                  \
        int r_ = R0 - 2 + (T);                                                  \
        r_ = (r_ < 0) ? -r_ : ((r_ >= HH) ? (2*(HH-1) - r_) : r_);              \
        const int ro_ = r_ * WW;                                                \
        VA_ = *(const float4*)(pa + ro_ + gcol);                                \
        VB_ = *(const float4*)(pb + ro_ + gcol);                                \
        VC_ = *(const float4*)(pc + ro_ + gcol);                                \
        LA_ = *(const float4*)(pa + ro_ + cLo);                                 \
        LB_ = *(const float4*)(pb + ro_ + cLo);                                 \
        LC_ = *(const float4*)(pc + ro_ + cLo);                                 \
        RA_ = *(const float4*)(pa + ro_ + cHi);                                 \
        RB_ = *(const float4*)(pb + ro_ + cHi);                                 \
        RC_ = *(const float4*)(pc + ro_ + cHi);                                 \
    } while (0)

    // preload row-step 0
    LOADROW(0, va,vb,vc, vLa,vLb,vLc, vRa,vRb,vRc);

    #pragma unroll 1
    for (int tb = 0; tb < 8; ++tb) {
        #pragma unroll
        for (int u = 0; u < 5; ++u) {
            const int t = tb * 5 + u;          // row step; slot = u
            if (t < 36) {
                // ---- prefetch next row: whole body below is its cover ----
                if (t + 1 < 36)
                    LOADROW(t + 1, nva,nvb,nvc, nvLa,nvLb,nvLc, nvRa,nvRb,nvRc);

                // quantized gray (x255 domain), own 4 cols
                float g0 = gray255(quant255(va.x), quant255(vb.x), quant255(vc.x));
                float g1 = gray255(quant255(va.y), quant255(vb.y), quant255(vc.y));
                float g2 = gray255(quant255(va.z), quant255(vb.z), quant255(vc.z));
                float g3 = gray255(quant255(va.w), quant255(vb.w), quant255(vc.w));

                // raw halo directly from the aligned neighbor lines (no shuffles)
                float l2a = vLa.z, l1a = vLa.w, r0a = vRa.x, r1a = vRa.y;
                float l2b = vLb.z, l1b = vLb.w, r0b = vRb.x, r1b = vRb.y;
                float l2c = vLc.z, l1c = vLc.w, r0c = vRc.x, r1c = vRc.y;
                // gray halo via shuffle of computed gray (4 shuffles only)
                float gl2 = __shfl_up(g2, 1),   gl1 = __shfl_up(g3, 1);
                float gr0 = __shfl_down(g0, 1), gr1 = __shfl_down(g1, 1);

                if (lane == 0) {
                    if (X0 == 0) { // reflect-101: col -2 -> col 2 (.z), col -1 -> col 1 (.y)
                        l2a = va.z; l1a = va.y; l2b = vb.z; l1b = vb.y; l2c = vc.z; l1c = vc.y;
                        gl2 = g2;   gl1 = g1;
                    } else {       // raw halo already valid (vL = cols 252..255);
                                   // gray halo must be recomputed (shuffle gave own value)
                        gl2 = gray255(quant255(vLa.z), quant255(vLb.z), quant255(vLc.z));
                        gl1 = gray255(quant255(vLa.w), quant255(vLb.w), quant255(vLc.w));
                    }
                }
                if (lane == 63) {
                    if (X0 == 0) { // raw halo valid (vR = cols 256..259); recompute gray halo
                        gr0 = gray255(quant255(vRa.x), quant255(vRb.x), quant255(vRc.x));
                        gr1 = gray255(quant255(vRa.y), quant255(vRb.y), quant255(vRc.y));
                    } else {       // reflect-101: col 512 -> 510 (.z), col 513 -> 509 (.y)
                        r0a = va.z; r1a = va.y; r0b = vb.z; r1b = vb.y; r0c = vc.z; r1c = vc.y;
                        gr0 = g2;   gr1 = g1;
                    }
                }

                // horizontal blur of row t -> ring slot u
                hrA[u][0] = GK0*(l2a+va.z) + GK1*(l1a+va.y) + GK2*va.x;
                hrA[u][1] = GK0*(l1a+va.w) + GK1*(va.x+va.z) + GK2*va.y;
                hrA[u][2] = GK0*(va.x+r0a) + GK1*(va.y+va.w) + GK2*va.z;
                hrA[u][3] = GK0*(va.y+r1a) + GK1*(va.z+r0a) + GK2*va.w;
                hrB[u][0] = GK0*(l2b+vb.z) + GK1*(l1b+vb.y) + GK2*vb.x;
                hrB[u][1] = GK0*(l1b+vb.w) + GK1*(vb.x+vb.z) + GK2*vb.y;
                hrB[u][2] = GK0*(vb.x+r0b) + GK1*(vb.y+vb.w) + GK2*vb.z;
                hrB[u][3] = GK0*(vb.y+r1b) + GK1*(vb.z+r0b) + GK2*vb.w;
                hrC[u][0] = GK0*(l2c+vc.z) + GK1*(l1c+vc.y) + GK2*vc.x;
                hrC[u][1] = GK0*(l1c+vc.w) + GK1*(vc.x+vc.z) + GK2*vc.y;
                hrC[u][2] = GK0*(vc.x+r0c) + GK1*(vc.y+vc.w) + GK2*vc.z;
                hrC[u][3] = GK0*(vc.y+r1c) + GK1*(vc.z+r0c) + GK2*vc.w;
                hrG[u][0] = GK0*(gl2+g2) + GK1*(gl1+g1) + GK2*g0;
                hrG[u][1] = GK0*(gl1+g3) + GK1*(g0+g2)  + GK2*g1;
                hrG[u][2] = GK0*(g0+gr0) + GK1*(g1+g3)  + GK2*g2;
                hrG[u][3] = GK0*(g1+gr1) + GK1*(g2+gr0) + GK2*g3;

                // output: center row t-2 (valid for t in [4,35])
                if (t >= 4) {
                    const int s0=(u+1)%5, s1=(u+2)%5, s2=(u+3)%5, s3=(u+4)%5, s4=u;
                    #pragma unroll
                    for (int j = 0; j < 4; ++j) {
                        float bl, v;
                        bl = GK0*(hrA[s0][j]+hrA[s4][j]) + GK1*(hrA[s1][j]+hrA[s3][j]) + GK2*hrA[s2][j];
                        v  = d2A[j] - bl;  sA += v;  qA = fmaf(v, v, qA);
                        bl = GK0*(hrB[s0][j]+hrB[s4][j]) + GK1*(hrB[s1][j]+hrB[s3][j]) + GK2*hrB[s2][j];
                        v  = d2B[j] - bl;  sB += v;  qB = fmaf(v, v, qB);
                        bl = GK0*(hrC[s0][j]+hrC[s4][j]) + GK1*(hrC[s1][j]+hrC[s3][j]) + GK2*hrC[s2][j];
                        v  = d2C[j] - bl;  sC += v;  qC = fmaf(v, v, qC);
                        bl = GK0*(hrG[s0][j]+hrG[s4][j]) + GK1*(hrG[s1][j]+hrG[s3][j]) + GK2*hrG[s2][j];
                        v  = d2G[j] - bl;  sG += v;  qG = fmaf(v, v, qG);
                        // histogram: x255 domain, bins over (-0.5,0.5)*255, right edge inclusive
                        if (v >= -127.5f && v <= 127.5f) {
                            int idx = (int)((v + 127.5f) * 0.19607843137254902f); // 50/255
                            idx = idx > 49 ? 49 : idx;
                            atomicAdd(&lhist[wid][lane & 1][idx], 1u);
                        }
                    }
                }

                // shift raw-center delays
                #pragma unroll
                for (int j = 0; j < 4; ++j) { d2A[j]=d1A[j]; d2B[j]=d1B[j]; d2C[j]=d1C[j]; d2G[j]=d1G[j]; }
                d1A[0]=va.x; d1A[1]=va.y; d1A[2]=va.z; d1A[3]=va.w;
                d1B[0]=vb.x; d1B[1]=vb.y; d1B[2]=vb.z; d1B[3]=vb.w;
                d1C[0]=vc.x; d1C[1]=vc.y; d1C[2]=vc.z; d1C[3]=vc.w;
                d1G[0]=g0;   d1G[1]=g1;   d1G[2]=g2;   d1G[3]=g3;

                // rotate prefetched row into current (renamed away inside the unroll)
                va  = nva;  vb  = nvb;  vc  = nvc;
                vLa = nvLa; vLb = nvLb; vLc = nvLc;
                vRa = nvRa; vRb = nvRb; vRc = nvRc;
            }
        }
    }
#undef LOADROW

    // wave-reduce 8 accumulators -> one global atomic each
    float acc[8] = {sA, qA, sB, qB, sC, qC, sG, qG};
    #pragma unroll
    for (int f = 0; f < 8; ++f) {
        float v = acc[f];
        #pragma unroll
        for (int o = 32; o > 0; o >>= 1) v += __shfl_down(v, o);
        if (lane == 0) atomicAdd(&gsums[b*8 + f], v);
    }
    __syncthreads();
    if (tid < 50) {
        unsigned int h = lhist[0][0][tid] + lhist[0][1][tid]
                       + lhist[1][0][tid] + lhist[1][1][tid]
                       + lhist[2][0][tid] + lhist[2][1][tid]
                       + lhist[3][0][tid] + lhist[3][1][tid];
        atomicAdd(&ghist[b*50 + tid], h);
    }
}

// One lane per image: stats -> feats[6] -> 6->32->64 ReLU MLP
__global__ __launch_bounds__(64)
void noise_final(const float* __restrict__ gsums, const unsigned int* __restrict__ ghist,
                 const float* __restrict__ W1, const float* __restrict__ b1,
                 const float* __restrict__ W2, const float* __restrict__ b2,
                 float* __restrict__ out)
{
    const int b = threadIdx.x;
    if (b >= NB) return;
    const float invN = 1.0f / (float)(HH*WW);
    float feats[6];
    {   // gray variance/std (undo x255 scaling)
        float s = gsums[b*8 + 6], q = gsums[b*8 + 7];
        float m = s * invN;
        float var255 = q * invN - m*m;
        var255 = var255 < 0.f ? 0.f : var255;
        float var = var255 * (1.0f/65025.0f);
        feats[0] = var; feats[1] = sqrtf(var);
    }
    {   // histogram entropy
        float tot = 0.f;
        for (int i = 0; i < 50; ++i) tot += (float)ghist[b*50 + i];
        float inv = 1.0f / (tot + 1e-10f);
        float e = 0.f;
        for (int i = 0; i < 50; ++i) {
            float p = (float)ghist[b*50 + i] * inv;
            e -= p * log2f(p + 1e-10f);
        }
        feats[2] = e;
    }
    for (int c = 0; c < 3; ++c) {
        float s = gsums[b*8 + 2*c], q = gsums[b*8 + 2*c + 1];
        float m = s * invN;
        float v = q * invN - m*m;
        feats[3+c] = sqrtf(v < 0.f ? 0.f : v);
    }
    float h[32];
    #pragma unroll
    for (int i = 0; i < 32; ++i) {
        float a = b1[i];
        #pragma unroll
        for (int j = 0; j < 6; ++j) a = fmaf(feats[j], W1[i*6 + j], a);
        h[i] = a > 0.f ? a : 0.f;
    }
    for (int k = 0; k < 64; ++k) {
        float a = b2[k];
        #pragma unroll
        for (int j = 0; j < 32; ++j) a = fmaf(h[j], W2[k*32 + j], a);
        out[b*64 + k] = a > 0.f ? a : 0.f;
    }
}

extern "C" void kernel_launch(void* const* d_in, const int* in_sizes, int n_in,
                              void* d_out, int out_size, void* d_ws, size_t ws_size,
                              hipStream_t stream) {
    (void)in_sizes; (void)n_in; (void)out_size; (void)ws_size;
    const float* x  = (const float*)d_in[0];
    const float* W1 = (const float*)d_in[1];
    const float* b1 = (const float*)d_in[2];
    const float* W2 = (const float*)d_in[3];
    const float* b2 = (const float*)d_in[4];
    float* out = (float*)d_out;

    float* gsums = (float*)d_ws;                                   // [64][8]
    unsigned int* ghist = (unsigned int*)((char*)d_ws + NB*8*4);   // [64][50]
    hipMemsetAsync(d_ws, 0, NB*8*4 + NB*50*4, stream);

    hipLaunchKernelGGL(noise_main, dim3(512), dim3(256), 0, stream, x, gsums, ghist);
    hipLaunchKernelGGL(noise_final, dim3(1), dim3(64), 0, stream,
                       gsums, ghist, W1, b1, W2, b2, out);
}